// Round 1
// baseline (2503.171 us; speedup 1.0000x reference)
//
#include <hip/hip_runtime.h>
#include <hip/hip_bf16.h>

// MoE dense layer: out[n,r] = sum_e softmax(x@gw+gb)[n,e] * (x @ W_e + b_e)[n,r]
// N = D_IN = D_OUT = 4096, E = 8.
//
// Fast path (needs ~302MB ws):
//   k1: x fp32 -> x_bf16 (row-major [4096][4096])
//   k2: gate softmax -> gate[4096][8] fp32
//   k3: expert_w fp32 [32768][4096] -> Bt bf16 [4096][32768] (transpose+convert)
//   k4: single GEMM M=4096,N=4096,K=32768 (experts concatenated along K),
//       per-expert gate weighting folded in via in-place accumulator rescale
//       acc *= g[e]/g[e+1] at expert boundaries (online-softmax-style trick).
// Fallback (ws too small): fp32 vector GEMM, correct but slow.

typedef __attribute__((ext_vector_type(8))) short short8;   // 8 bf16 in 4 VGPRs
typedef __attribute__((ext_vector_type(4))) float f32x4;

#define NROWS 4096
#define DIN   4096
#define DOUT  4096
#define NEXP  8
#define KTOT  (NEXP * DIN)   // 32768

// ---------- helpers ----------
__device__ __forceinline__ unsigned short f2b(float f) {
  unsigned int u = __float_as_uint(f);
  u += 0x7FFFu + ((u >> 16) & 1u);   // round-to-nearest-even
  return (unsigned short)(u >> 16);
}

__device__ __forceinline__ void gload_lds16(const unsigned short* g, unsigned short* l) {
  // global -> LDS direct DMA, 16B/lane; LDS dest = wave-uniform base + lane*16.
  __builtin_amdgcn_global_load_lds(
      (const __attribute__((address_space(1))) unsigned int*)(unsigned long long)g,
      (__attribute__((address_space(3))) unsigned int*)(unsigned int)(unsigned long long)l,
      16, 0, 0);
}

// ---------- k1: x -> bf16 ----------
__global__ __launch_bounds__(256) void convert_x(const float* __restrict__ in,
                                                 unsigned short* __restrict__ outb) {
  size_t i = ((size_t)blockIdx.x * 256 + threadIdx.x) * 8;
  float4 a = *(const float4*)(in + i);
  float4 b = *(const float4*)(in + i + 4);
  union { unsigned short u[8]; uint4 v; } r;
  r.u[0] = f2b(a.x); r.u[1] = f2b(a.y); r.u[2] = f2b(a.z); r.u[3] = f2b(a.w);
  r.u[4] = f2b(b.x); r.u[5] = f2b(b.y); r.u[6] = f2b(b.z); r.u[7] = f2b(b.w);
  *(uint4*)(outb + i) = r.v;
}

// ---------- k2: gate softmax ----------
__global__ __launch_bounds__(256) void gate_kernel(const float* __restrict__ x,
                                                   const float* __restrict__ gw,
                                                   const float* __restrict__ gb,
                                                   float* __restrict__ g) {
  __shared__ float red[256][8];
  const int n = blockIdx.x, t = threadIdx.x;
  float a[8] = {0, 0, 0, 0, 0, 0, 0, 0};
  for (int d = t; d < DIN; d += 256) {
    float xv = x[(size_t)n * DIN + d];
    const float4* gwp = (const float4*)(gw + (size_t)d * 8);
    float4 w0 = gwp[0], w1 = gwp[1];
    a[0] += xv * w0.x; a[1] += xv * w0.y; a[2] += xv * w0.z; a[3] += xv * w0.w;
    a[4] += xv * w1.x; a[5] += xv * w1.y; a[6] += xv * w1.z; a[7] += xv * w1.w;
  }
  for (int e = 0; e < 8; ++e) red[t][e] = a[e];
  __syncthreads();
  for (int s = 128; s > 0; s >>= 1) {
    if (t < s)
      for (int e = 0; e < 8; ++e) red[t][e] += red[t + s][e];
    __syncthreads();
  }
  if (t == 0) {
    float l[8], m = -1e30f, ssum = 0.f;
    for (int e = 0; e < 8; ++e) { l[e] = red[0][e] + gb[e]; m = fmaxf(m, l[e]); }
    for (int e = 0; e < 8; ++e) { l[e] = expf(l[e] - m); ssum += l[e]; }
    for (int e = 0; e < 8; ++e) g[(size_t)n * 8 + e] = l[e] / ssum;
  }
}

// ---------- k3: expert_w [32768][4096] fp32 -> Bt [4096][32768] bf16 ----------
__global__ __launch_bounds__(256) void transpose_w(const float* __restrict__ W,
                                                   unsigned short* __restrict__ bt) {
  __shared__ unsigned short tile[64][68];   // pad 68: 136B rows, 8B aligned
  const int t = threadIdx.x;
  const int k0 = blockIdx.x * 64, r0 = blockIdx.y * 64;
  #pragma unroll
  for (int i = 0; i < 16; ++i) {
    int lin = i * 256 + t;
    int kr = lin >> 6, rr = lin & 63;
    tile[rr][kr] = f2b(W[(size_t)(k0 + kr) * 4096 + r0 + rr]);
  }
  __syncthreads();
  #pragma unroll
  for (int i = 0; i < 4; ++i) {
    int lin = i * 256 + t;            // 0..1023
    int rr = lin >> 4, kc = (lin & 15) * 4;
    uint2 v = *(const uint2*)&tile[rr][kc];
    *(uint2*)(bt + (size_t)(r0 + rr) * KTOT + k0 + kc) = v;
  }
}

// ---------- k4: main GEMM, K=32768, per-expert acc rescale ----------
__global__ __launch_bounds__(256) void gemm_moe(const unsigned short* __restrict__ xb,
                                                const unsigned short* __restrict__ bt,
                                                const float* __restrict__ gate,
                                                const float* __restrict__ eb,
                                                float* __restrict__ out) {
  __shared__ alignas(16) unsigned short sA[128 * 64];  // [row][k] 16KB
  __shared__ alignas(16) unsigned short sB[128 * 64];  // [col r][k] 16KB
  __shared__ float sG[128 * 8];                        // gate rows
  __shared__ float sBias[8 * 128];                     // expert_b cols

  const int t = threadIdx.x;
  const int lane = t & 63;
  const int w = t >> 6;            // wave 0..3
  const int wm = w >> 1, wn = w & 1;

  // block swizzle: 8x8 tile groups for LLC locality (A+B working set 128MB/group)
  const int bid = blockIdx.x;
  const int grp = bid >> 6, wi = bid & 63;
  const int row0 = ((grp >> 2) * 8 + (wi >> 3)) * 128;
  const int col0 = ((grp & 3) * 8 + (wi & 7)) * 128;

  // prologue: gate + bias tiles
  #pragma unroll
  for (int i = 0; i < 4; ++i) {
    int lin = i * 256 + t;
    sG[lin] = gate[(size_t)row0 * 8 + lin];
    sBias[lin] = eb[(size_t)(lin >> 7) * DOUT + col0 + (lin & 127)];
  }

  const int laneRow = lane >> 3;          // 0..7
  const int laneK8 = (lane & 7) * 8;      // 0..56
  const int mrow = lane & 15;
  const int quad = lane >> 4;

  f32x4 acc[4][4];
  #pragma unroll
  for (int i = 0; i < 4; ++i)
    #pragma unroll
    for (int j = 0; j < 4; ++j) acc[i][j] = (f32x4){0.f, 0.f, 0.f, 0.f};

  const size_t aRowBase = (size_t)(row0 + w * 32 + laneRow) * DIN;
  const size_t bRowBase = (size_t)(col0 + w * 32 + laneRow) * KTOT;

  for (int kt = 0; kt < KTOT / 64; ++kt) {
    const int k0 = kt * 64;
    // expert index for this K-chunk: e = k0 / 4096; within-expert k = k0 % 4096
    const int kx = k0 & (DIN - 1);
    // stage A (x_bf16) and B (Bt) tiles via direct-to-LDS, 16B/lane
    #pragma unroll
    for (int j = 0; j < 4; ++j) {
      gload_lds16(xb + aRowBase + (size_t)j * 8 * DIN + kx + laneK8,
                  &sA[(w * 32 + j * 8) * 64]);
      gload_lds16(bt + bRowBase + (size_t)j * 8 * KTOT + k0 + laneK8,
                  &sB[(w * 32 + j * 8) * 64]);
    }
    __syncthreads();   // compiler drains vmcnt before barrier

    #pragma unroll
    for (int kk = 0; kk < 2; ++kk) {
      short8 af[4], bf[4];
      #pragma unroll
      for (int i = 0; i < 4; ++i)
        af[i] = *(const short8*)&sA[(wm * 64 + i * 16 + mrow) * 64 + kk * 32 + quad * 8];
      #pragma unroll
      for (int j = 0; j < 4; ++j)
        bf[j] = *(const short8*)&sB[(wn * 64 + j * 16 + mrow) * 64 + kk * 32 + quad * 8];
      #pragma unroll
      for (int i = 0; i < 4; ++i)
        #pragma unroll
        for (int j = 0; j < 4; ++j)
          acc[i][j] = __builtin_amdgcn_mfma_f32_16x16x32_bf16(af[i], bf[j], acc[i][j], 0, 0, 0);
    }
    __syncthreads();

    // expert boundary: fold gate weight via in-place rescale.
    // After expert e, acc holds (sum_{i<=e} g_i P_i)/g_e; epilogue scales by g_7.
    if ((kt & 63) == 63 && kt != (KTOT / 64 - 1)) {
      const int e = kt >> 6;
      #pragma unroll
      for (int i = 0; i < 4; ++i) {
        #pragma unroll
        for (int r = 0; r < 4; ++r) {
          const int row_l = wm * 64 + i * 16 + quad * 4 + r;
          const float s = sG[row_l * 8 + e] / sG[row_l * 8 + e + 1];
          #pragma unroll
          for (int j = 0; j < 4; ++j) acc[i][j][r] *= s;
        }
      }
    }
  }

  // epilogue: *g7, + sum_e g_e * b_e[col]
  #pragma unroll
  for (int i = 0; i < 4; ++i) {
    #pragma unroll
    for (int r = 0; r < 4; ++r) {
      const int row_l = wm * 64 + i * 16 + quad * 4 + r;
      float gv[8];
      #pragma unroll
      for (int e = 0; e < 8; ++e) gv[e] = sG[row_l * 8 + e];
      #pragma unroll
      for (int j = 0; j < 4; ++j) {
        const int col_l = wn * 64 + j * 16 + mrow;
        float bias = 0.f;
        #pragma unroll
        for (int e = 0; e < 8; ++e) bias += gv[e] * sBias[e * 128 + col_l];
        out[(size_t)(row0 + row_l) * DOUT + col0 + col_l] = acc[i][j][r] * gv[7] + bias;
      }
    }
  }
}

// ---------- fallback: fp32, no workspace ----------
__global__ __launch_bounds__(256) void moe_fallback(const float* __restrict__ x,
                                                    const float* __restrict__ gw,
                                                    const float* __restrict__ gb,
                                                    const float* __restrict__ W,
                                                    const float* __restrict__ eb,
                                                    float* __restrict__ out) {
  __shared__ float sX[64][33];
  __shared__ float sW[32][65];
  __shared__ float sLog[64][8];
  __shared__ float sGate[64][8];
  const int t = threadIdx.x;
  const int r0 = blockIdx.y * 64, c0 = blockIdx.x * 64;

  // gate phase
  const int grow = t & 63, epair = t >> 6;
  float lg0 = gb[2 * epair], lg1 = gb[2 * epair + 1];
  for (int d0 = 0; d0 < DIN; d0 += 32) {
    for (int i = 0; i < 8; ++i) {
      int lin = i * 256 + t, rr = lin >> 5, cc = lin & 31;
      sX[rr][cc] = x[(size_t)(r0 + rr) * DIN + d0 + cc];
    }
    __syncthreads();
    for (int dd = 0; dd < 32; ++dd) {
      float xv = sX[grow][dd];
      lg0 += xv * gw[(size_t)(d0 + dd) * 8 + 2 * epair];
      lg1 += xv * gw[(size_t)(d0 + dd) * 8 + 2 * epair + 1];
    }
    __syncthreads();
  }
  sLog[grow][2 * epair] = lg0;
  sLog[grow][2 * epair + 1] = lg1;
  __syncthreads();
  if (t < 64) {
    float m = -1e30f, s = 0.f, ex[8];
    for (int e = 0; e < 8; ++e) m = fmaxf(m, sLog[t][e]);
    for (int e = 0; e < 8; ++e) { ex[e] = expf(sLog[t][e] - m); s += ex[e]; }
    for (int e = 0; e < 8; ++e) sGate[t][e] = ex[e] / s;
  }
  __syncthreads();

  const int tr = t >> 4, tc = t & 15;
  float acc[4][4] = {};
  for (int e = 0; e < NEXP; ++e) {
    float part[4][4] = {};
    for (int d0 = 0; d0 < DIN; d0 += 32) {
      for (int i = 0; i < 8; ++i) {
        int lin = i * 256 + t, rr = lin >> 5, cc = lin & 31;
        sX[rr][cc] = x[(size_t)(r0 + rr) * DIN + d0 + cc];
      }
      for (int i = 0; i < 8; ++i) {
        int lin = i * 256 + t, dd = lin >> 6, cc = lin & 63;
        sW[dd][cc] = W[(size_t)e * DIN * DOUT + (size_t)(d0 + dd) * DOUT + c0 + cc];
      }
      __syncthreads();
      for (int dd = 0; dd < 32; ++dd) {
        float xa[4], wb[4];
        for (int i = 0; i < 4; ++i) xa[i] = sX[tr + 16 * i][dd];
        for (int j = 0; j < 4; ++j) wb[j] = sW[dd][tc + 16 * j];
        for (int i = 0; i < 4; ++i)
          for (int j = 0; j < 4; ++j) part[i][j] += xa[i] * wb[j];
      }
      __syncthreads();
    }
    for (int i = 0; i < 4; ++i) {
      float g = sGate[tr + 16 * i][e];
      for (int j = 0; j < 4; ++j)
        acc[i][j] += g * (part[i][j] + eb[(size_t)e * DOUT + c0 + tc + 16 * j]);
    }
  }
  for (int i = 0; i < 4; ++i)
    for (int j = 0; j < 4; ++j)
      out[(size_t)(r0 + tr + 16 * i) * DOUT + c0 + tc + 16 * j] = acc[i][j];
}

extern "C" void kernel_launch(void* const* d_in, const int* in_sizes, int n_in,
                              void* d_out, int out_size, void* d_ws, size_t ws_size,
                              hipStream_t stream) {
  const float* x  = (const float*)d_in[0];
  const float* gw = (const float*)d_in[1];
  const float* gb = (const float*)d_in[2];
  const float* W  = (const float*)d_in[3];
  const float* eb = (const float*)d_in[4];
  float* out = (float*)d_out;

  const size_t sz_xb = (size_t)NROWS * DIN * 2;          // 32MB
  const size_t sz_bt = (size_t)DOUT * KTOT * 2;          // 256MB
  const size_t sz_g  = (size_t)NROWS * 8 * 4;            // 128KB
  const size_t need = sz_xb + sz_bt + sz_g;

  if (ws_size >= need) {
    unsigned short* xb = (unsigned short*)d_ws;
    unsigned short* bt = (unsigned short*)((char*)d_ws + sz_xb);
    float* gate = (float*)((char*)d_ws + sz_xb + sz_bt);
    convert_x<<<(NROWS * (size_t)DIN) / (8 * 256), 256, 0, stream>>>(x, xb);
    gate_kernel<<<NROWS, 256, 0, stream>>>(x, gw, gb, gate);
    transpose_w<<<dim3(KTOT / 64, DOUT / 64), 256, 0, stream>>>(W, bt);
    gemm_moe<<<(NROWS / 128) * (DOUT / 128), 256, 0, stream>>>(xb, bt, gate, eb, out);
  } else {
    moe_fallback<<<dim3(DOUT / 64, NROWS / 64), 256, 0, stream>>>(x, gw, gb, W, eb, out);
  }
}

// Round 2
// 2147.223 us; speedup vs baseline: 1.1658x; 1.1658x over previous
//
#include <hip/hip_runtime.h>
#include <hip/hip_bf16.h>

// MoE dense layer: out[n,r] = sum_e softmax(x@gw+gb)[n,e] * (x @ W_e + b_e)[n,r]
// N = D_IN = D_OUT = 4096, E = 8.
//
// Fast path (needs ~302MB ws):
//   k1: gate softmax -> gate[4096][8] fp32, fused with x fp32 -> x_bf16
//   k2: expert_w fp32 [32768][4096] -> Bt bf16 [4096][32768] (transpose+convert)
//   k3: single GEMM M=4096,N=4096,K=32768 (experts concatenated along K),
//       gate weighting folded via in-place accumulator rescale at expert
//       boundaries (online-softmax-style). LDS tiles use a 16B-granule XOR
//       swizzle (slot = g ^ (row&7)) to kill ds_read_b128 bank conflicts;
//       the swizzle is applied on the *global* address of global_load_lds.

typedef __attribute__((ext_vector_type(8))) short short8;   // 8 bf16 in 4 VGPRs
typedef __attribute__((ext_vector_type(4))) float f32x4;

#define NROWS 4096
#define DIN   4096
#define DOUT  4096
#define NEXP  8
#define KTOT  (NEXP * DIN)   // 32768

// ---------- helpers ----------
__device__ __forceinline__ unsigned short f2b(float f) {
  unsigned int u = __float_as_uint(f);
  u += 0x7FFFu + ((u >> 16) & 1u);   // round-to-nearest-even
  return (unsigned short)(u >> 16);
}

__device__ __forceinline__ void gload_lds16(const unsigned short* g, unsigned short* l) {
  // global -> LDS direct DMA, 16B/lane; LDS dest = wave-uniform base + lane*16.
  __builtin_amdgcn_global_load_lds(
      (const __attribute__((address_space(1))) unsigned int*)(unsigned long long)g,
      (__attribute__((address_space(3))) unsigned int*)(unsigned int)(unsigned long long)l,
      16, 0, 0);
}

// ---------- k1: gate softmax + x->bf16 (fused; one block per row) ----------
__global__ __launch_bounds__(256) void gate_kernel(const float* __restrict__ x,
                                                   const float* __restrict__ gw,
                                                   const float* __restrict__ gb,
                                                   float* __restrict__ g,
                                                   unsigned short* __restrict__ xb) {
  __shared__ float red[256][8];
  const int n = blockIdx.x, t = threadIdx.x;
  float a[8] = {0, 0, 0, 0, 0, 0, 0, 0};
  for (int d = t; d < DIN; d += 256) {
    float xv = x[(size_t)n * DIN + d];
    xb[(size_t)n * DIN + d] = f2b(xv);          // fused conversion
    const float4* gwp = (const float4*)(gw + (size_t)d * 8);
    float4 w0 = gwp[0], w1 = gwp[1];
    a[0] += xv * w0.x; a[1] += xv * w0.y; a[2] += xv * w0.z; a[3] += xv * w0.w;
    a[4] += xv * w1.x; a[5] += xv * w1.y; a[6] += xv * w1.z; a[7] += xv * w1.w;
  }
  for (int e = 0; e < 8; ++e) red[t][e] = a[e];
  __syncthreads();
  for (int s = 128; s > 0; s >>= 1) {
    if (t < s)
      for (int e = 0; e < 8; ++e) red[t][e] += red[t + s][e];
    __syncthreads();
  }
  if (t == 0) {
    float l[8], m = -1e30f, ssum = 0.f;
    for (int e = 0; e < 8; ++e) { l[e] = red[0][e] + gb[e]; m = fmaxf(m, l[e]); }
    for (int e = 0; e < 8; ++e) { l[e] = expf(l[e] - m); ssum += l[e]; }
    for (int e = 0; e < 8; ++e) g[(size_t)n * 8 + e] = l[e] / ssum;
  }
}

// ---------- k2: expert_w [32768][4096] fp32 -> Bt [4096][32768] bf16 ----------
// 64k x 64r tiles; float4 global reads, uint4 LDS reads + global writes.
__global__ __launch_bounds__(256) void transpose_w(const float* __restrict__ W,
                                                   unsigned short* __restrict__ bt) {
  __shared__ unsigned short tile[64][72];   // 144B rows -> uint4-aligned at 16B steps
  const int t = threadIdx.x;
  const int k0 = blockIdx.x * 64, r0 = blockIdx.y * 64;
  #pragma unroll
  for (int i = 0; i < 4; ++i) {
    int lin = i * 256 + t;                 // 0..1023
    int kr = lin >> 4, rq = (lin & 15) * 4;
    float4 v = *(const float4*)(W + (size_t)(k0 + kr) * 4096 + r0 + rq);
    tile[rq + 0][kr] = f2b(v.x);
    tile[rq + 1][kr] = f2b(v.y);
    tile[rq + 2][kr] = f2b(v.z);
    tile[rq + 3][kr] = f2b(v.w);
  }
  __syncthreads();
  #pragma unroll
  for (int i = 0; i < 2; ++i) {
    int lin = i * 256 + t;                 // 0..511
    int rr = lin >> 3, kc = (lin & 7) * 8;
    uint4 v = *(const uint4*)&tile[rr][kc];
    *(uint4*)(bt + (size_t)(r0 + rr) * KTOT + k0 + kc) = v;
  }
}

// ---------- k3: main GEMM, K=32768, swizzled LDS, per-expert acc rescale ----------
__global__ __launch_bounds__(256) void gemm_moe(const unsigned short* __restrict__ xb,
                                                const unsigned short* __restrict__ bt,
                                                const float* __restrict__ gate,
                                                const float* __restrict__ eb,
                                                float* __restrict__ out) {
  __shared__ alignas(16) unsigned short sA[128 * 64];  // [row][k-slot] 16KB, swizzled
  __shared__ alignas(16) unsigned short sB[128 * 64];  // [col][k-slot] 16KB, swizzled
  __shared__ float sG[128 * 8];                        // gate rows
  __shared__ float sBias[8 * 128];                     // expert_b cols

  const int t = threadIdx.x;
  const int lane = t & 63;
  const int w = t >> 6;            // wave 0..3
  const int wm = w >> 1, wn = w & 1;

  // block swizzle: 8x8 tile groups for LLC locality
  const int bid = blockIdx.x;
  const int grp = bid >> 6, wi = bid & 63;
  const int row0 = ((grp >> 2) * 8 + (wi >> 3)) * 128;
  const int col0 = ((grp & 3) * 8 + (wi & 7)) * 128;

  // prologue: gate + bias tiles
  #pragma unroll
  for (int i = 0; i < 4; ++i) {
    int lin = i * 256 + t;
    sG[lin] = gate[(size_t)row0 * 8 + lin];
    sBias[lin] = eb[(size_t)(lin >> 7) * DOUT + col0 + (lin & 127)];
  }

  const int laneRow = lane >> 3;                        // 0..7
  const int swzK8 = (((lane & 7) ^ laneRow) * 8);       // swizzled 16B granule
  const int mrow = lane & 15;
  const int quad = lane >> 4;

  f32x4 acc[4][4];
  #pragma unroll
  for (int i = 0; i < 4; ++i)
    #pragma unroll
    for (int j = 0; j < 4; ++j) acc[i][j] = (f32x4){0.f, 0.f, 0.f, 0.f};

  const size_t aRowBase = (size_t)(row0 + w * 32 + laneRow) * DIN;
  const size_t bRowBase = (size_t)(col0 + w * 32 + laneRow) * KTOT;

  for (int kt = 0; kt < KTOT / 64; ++kt) {
    const int k0 = kt * 64;
    const int kx = k0 & (DIN - 1);       // A (=x) wraps every expert
    #pragma unroll
    for (int j = 0; j < 4; ++j) {
      gload_lds16(xb + aRowBase + (size_t)j * 8 * DIN + kx + swzK8,
                  &sA[(w * 32 + j * 8) * 64]);
      gload_lds16(bt + bRowBase + (size_t)j * 8 * KTOT + k0 + swzK8,
                  &sB[(w * 32 + j * 8) * 64]);
    }
    __syncthreads();

    #pragma unroll
    for (int kk = 0; kk < 2; ++kk) {
      short8 af[4], bf[4];
      #pragma unroll
      for (int i = 0; i < 4; ++i) {
        const int R = wm * 64 + i * 16 + mrow;
        af[i] = *(const short8*)&sA[R * 64 + (((kk << 2) + quad) ^ (mrow & 7)) * 8];
      }
      #pragma unroll
      for (int j = 0; j < 4; ++j) {
        const int R = wn * 64 + j * 16 + mrow;
        bf[j] = *(const short8*)&sB[R * 64 + (((kk << 2) + quad) ^ (mrow & 7)) * 8];
      }
      #pragma unroll
      for (int i = 0; i < 4; ++i)
        #pragma unroll
        for (int j = 0; j < 4; ++j)
          acc[i][j] = __builtin_amdgcn_mfma_f32_16x16x32_bf16(af[i], bf[j], acc[i][j], 0, 0, 0);
    }
    __syncthreads();

    // expert boundary: fold gate weight via in-place rescale.
    if ((kt & 63) == 63 && kt != (KTOT / 64 - 1)) {
      const int e = kt >> 6;
      #pragma unroll
      for (int i = 0; i < 4; ++i) {
        #pragma unroll
        for (int r = 0; r < 4; ++r) {
          const int row_l = wm * 64 + i * 16 + quad * 4 + r;
          const float s = sG[row_l * 8 + e] / sG[row_l * 8 + e + 1];
          #pragma unroll
          for (int j = 0; j < 4; ++j) acc[i][j][r] *= s;
        }
      }
    }
  }

  // epilogue: *g7, + sum_e g_e * b_e[col]
  #pragma unroll
  for (int i = 0; i < 4; ++i) {
    #pragma unroll
    for (int r = 0; r < 4; ++r) {
      const int row_l = wm * 64 + i * 16 + quad * 4 + r;
      float gv[8];
      #pragma unroll
      for (int e = 0; e < 8; ++e) gv[e] = sG[row_l * 8 + e];
      #pragma unroll
      for (int j = 0; j < 4; ++j) {
        const int col_l = wn * 64 + j * 16 + mrow;
        float bias = 0.f;
        #pragma unroll
        for (int e = 0; e < 8; ++e) bias += gv[e] * sBias[e * 128 + col_l];
        out[(size_t)(row0 + row_l) * DOUT + col0 + col_l] = acc[i][j][r] * gv[7] + bias;
      }
    }
  }
}

// ---------- fallback: fp32, no workspace ----------
__global__ __launch_bounds__(256) void moe_fallback(const float* __restrict__ x,
                                                    const float* __restrict__ gw,
                                                    const float* __restrict__ gb,
                                                    const float* __restrict__ W,
                                                    const float* __restrict__ eb,
                                                    float* __restrict__ out) {
  __shared__ float sX[64][33];
  __shared__ float sW[32][65];
  __shared__ float sLog[64][8];
  __shared__ float sGate[64][8];
  const int t = threadIdx.x;
  const int r0 = blockIdx.y * 64, c0 = blockIdx.x * 64;

  const int grow = t & 63, epair = t >> 6;
  float lg0 = gb[2 * epair], lg1 = gb[2 * epair + 1];
  for (int d0 = 0; d0 < DIN; d0 += 32) {
    for (int i = 0; i < 8; ++i) {
      int lin = i * 256 + t, rr = lin >> 5, cc = lin & 31;
      sX[rr][cc] = x[(size_t)(r0 + rr) * DIN + d0 + cc];
    }
    __syncthreads();
    for (int dd = 0; dd < 32; ++dd) {
      float xv = sX[grow][dd];
      lg0 += xv * gw[(size_t)(d0 + dd) * 8 + 2 * epair];
      lg1 += xv * gw[(size_t)(d0 + dd) * 8 + 2 * epair + 1];
    }
    __syncthreads();
  }
  sLog[grow][2 * epair] = lg0;
  sLog[grow][2 * epair + 1] = lg1;
  __syncthreads();
  if (t < 64) {
    float m = -1e30f, s = 0.f, ex[8];
    for (int e = 0; e < 8; ++e) m = fmaxf(m, sLog[t][e]);
    for (int e = 0; e < 8; ++e) { ex[e] = expf(sLog[t][e] - m); s += ex[e]; }
    for (int e = 0; e < 8; ++e) sGate[t][e] = ex[e] / s;
  }
  __syncthreads();

  const int tr = t >> 4, tc = t & 15;
  float acc[4][4] = {};
  for (int e = 0; e < NEXP; ++e) {
    float part[4][4] = {};
    for (int d0 = 0; d0 < DIN; d0 += 32) {
      for (int i = 0; i < 8; ++i) {
        int lin = i * 256 + t, rr = lin >> 5, cc = lin & 31;
        sX[rr][cc] = x[(size_t)(r0 + rr) * DIN + d0 + cc];
      }
      for (int i = 0; i < 8; ++i) {
        int lin = i * 256 + t, dd = lin >> 6, cc = lin & 63;
        sW[dd][cc] = W[(size_t)e * DIN * DOUT + (size_t)(d0 + dd) * DOUT + c0 + cc];
      }
      __syncthreads();
      for (int dd = 0; dd < 32; ++dd) {
        float xa[4], wb[4];
        for (int i = 0; i < 4; ++i) xa[i] = sX[tr + 16 * i][dd];
        for (int j = 0; j < 4; ++j) wb[j] = sW[dd][tc + 16 * j];
        for (int i = 0; i < 4; ++i)
          for (int j = 0; j < 4; ++j) part[i][j] += xa[i] * wb[j];
      }
      __syncthreads();
    }
    for (int i = 0; i < 4; ++i) {
      float g = sGate[tr + 16 * i][e];
      for (int j = 0; j < 4; ++j)
        acc[i][j] += g * (part[i][j] + eb[(size_t)e * DOUT + c0 + tc + 16 * j]);
    }
  }
  for (int i = 0; i < 4; ++i)
    for (int j = 0; j < 4; ++j)
      out[(size_t)(r0 + tr + 16 * i) * DOUT + c0 + tc + 16 * j] = acc[i][j];
}

extern "C" void kernel_launch(void* const* d_in, const int* in_sizes, int n_in,
                              void* d_out, int out_size, void* d_ws, size_t ws_size,
                              hipStream_t stream) {
  const float* x  = (const float*)d_in[0];
  const float* gw = (const float*)d_in[1];
  const float* gb = (const float*)d_in[2];
  const float* W  = (const float*)d_in[3];
  const float* eb = (const float*)d_in[4];
  float* out = (float*)d_out;

  const size_t sz_xb = (size_t)NROWS * DIN * 2;          // 32MB
  const size_t sz_bt = (size_t)DOUT * KTOT * 2;          // 256MB
  const size_t sz_g  = (size_t)NROWS * 8 * 4;            // 128KB
  const size_t need = sz_xb + sz_bt + sz_g;

  if (ws_size >= need) {
    unsigned short* xb = (unsigned short*)d_ws;
    unsigned short* bt = (unsigned short*)((char*)d_ws + sz_xb);
    float* gate = (float*)((char*)d_ws + sz_xb + sz_bt);
    gate_kernel<<<NROWS, 256, 0, stream>>>(x, gw, gb, gate, xb);
    transpose_w<<<dim3(KTOT / 64, DOUT / 64), 256, 0, stream>>>(W, bt);
    gemm_moe<<<(NROWS / 128) * (DOUT / 128), 256, 0, stream>>>(xb, bt, gate, eb, out);
  } else {
    moe_fallback<<<dim3(DOUT / 64, NROWS / 64), 256, 0, stream>>>(x, gw, gb, W, eb, out);
  }
}